// Round 13
// baseline (269.554 us; speedup 1.0000x reference)
//
#include <hip/hip_runtime.h>
#include <math.h>

#define NN 16384
#define NP 8192
#define NL 8192
#define KW 32
#define VC 100000
#define REVW 8
#define SENT  0xFFFFFFFFu
#define NEVER 0xFFFFFFFEu     // CAS compare that never matches real data -> pure coherent read
#define UMAP_NEGINF 0x007FFFFFu

__device__ __forceinline__ float sigmoidf_(float x){ return 1.0f/(1.0f+expf(-x)); }
__device__ __forceinline__ unsigned int umap(float f){
  unsigned int b = __float_as_uint(f);
  return (b & 0x80000000u) ? ~b : (b | 0x80000000u);
}
__device__ __forceinline__ float uunmap(unsigned int u){
  unsigned int b = (u & 0x80000000u) ? (u & 0x7FFFFFFFu) : ~u;
  return __uint_as_float(b);
}

// ---- K1: setup: ET transpose | WT | node_h->SENT | pact->SENT | sched state ----
// rcnt pre-zeroed by hipMemsetAsync (its atomicAdds need zero BEFORE any block runs).
__global__ void __launch_bounds__(256) k_setup(const float* __restrict__ E, float* __restrict__ ET,
    const float* __restrict__ Wz, const float* __restrict__ Wr, const float* __restrict__ Wh,
    const float* __restrict__ Uz, const float* __restrict__ Ur, const float* __restrict__ Uh,
    float* __restrict__ WT, unsigned int* node_h, unsigned int* pact,
    const int* __restrict__ tree, int* pending, int* rcnt, int* rev,
    int* g_rem, unsigned int* gmax, int et_blocks){
  __shared__ float tile[64][65];
  int b = blockIdx.x;
  int lane = threadIdx.x & 63, ty = threadIdx.x >> 6;
  if (b < et_blocks){
    int v0 = b*64;
    for (int h = ty; h < 64; h += 4){
      int v = v0 + lane;
      tile[h][lane] = (v < VC) ? E[(size_t)h*VC + v] : 0.f;
    }
    __syncthreads();
    for (int vv = ty; vv < 64; vv += 4){
      int v = v0 + vv;
      if (v < VC) ET[v*64 + lane] = tile[lane][vv];
    }
  } else if (b < et_blocks + 6){
    int m = b - et_blocks;
    const float* src = (m==0)?Wz:(m==1)?Wr:(m==2)?Wh:(m==3)?Uz:(m==4)?Ur:Uh;
    float* dst = WT + m*4096;
    for (int h = ty; h < 64; h += 4) tile[h][lane] = src[h*64 + lane];
    __syncthreads();
    for (int k = ty; k < 64; k += 4) dst[k*64 + lane] = tile[lane][k];
  } else if (b < et_blocks + 6 + 4096){
    size_t idx = (size_t)(b - et_blocks - 6)*256 + threadIdx.x;   // NN*64 dwords
    node_h[idx] = SENT;
  } else if (b < et_blocks + 6 + 4096 + 8192){
    size_t idx = (size_t)(b - et_blocks - 6 - 4096)*256 + threadIdx.x;  // NP*256 dwords
    pact[idx] = SENT;
  } else {
    int idx = (b - et_blocks - 6 - 4096 - 8192)*256 + threadIdx.x;
    if (idx < NP){
      const int* tr = tree + idx*5;
      int cnt = 0;
      #pragma unroll
      for (int j=0;j<4;++j){
        int c = tr[j];
        if (c >= NL){
          ++cnt;
          int cc = c - NL;
          int slot = atomicAdd(&rcnt[cc], 1);
          if (slot < REVW) rev[cc*REVW + slot] = idx;  // overflow -> finish backstop
        }
      }
      pending[idx] = cnt + 1;     // +1 = owner token
    }
    if (idx == 0) *g_rem = NP;
    if (idx < 512) gmax[idx] = UMAP_NEGINF;
  }
}

// ---- shared GRU math ----
__device__ __forceinline__ float gru_compute(int lane,
    int c0,int c1,int c2,int c3,
    float chv0,float chv1,float chv2,float chv3,
    float q, float pzv, float prv, float pcv,
    const float* __restrict__ UzT, const float* __restrict__ UrT,
    const float* __restrict__ UhT)
{
  float d0=q*chv0, d1=q*chv1, d2=q*chv2, d3=q*chv3;
  #pragma unroll
  for (int off=32; off; off>>=1){
    d0 += __shfl_xor(d0, off); d1 += __shfl_xor(d1, off);
    d2 += __shfl_xor(d2, off); d3 += __shfl_xor(d3, off);
  }
  float l0 = (c0>=0)? sigmoidf_(d0) : -1e30f;
  float l1 = (c1>=0)? sigmoidf_(d1) : -1e30f;
  float l2 = (c2>=0)? sigmoidf_(d2) : -1e30f;
  float l3 = (c3>=0)? sigmoidf_(d3) : -1e30f;
  float mx = fmaxf(fmaxf(l0,l1), fmaxf(l2,l3));
  float e0=expf(l0-mx), e1=expf(l1-mx), e2=expf(l2-mx), e3=expf(l3-mx);
  float inv = 1.f/(e0+e1+e2+e3);
  float ht = (e0*chv0 + e1*chv1 + e2*chv2 + e3*chv3)*inv;
  float az0=0.f, az1=0.f, ar0=0.f, ar1=0.f;
  #pragma unroll 8
  for (int k=0;k<64;k+=2){
    float h0 = __shfl(ht, k), h1 = __shfl(ht, k+1);
    az0 += h0 * UzT[k*64+lane];     az1 += h1 * UzT[(k+1)*64+lane];
    ar0 += h0 * UrT[k*64+lane];     ar1 += h1 * UrT[(k+1)*64+lane];
  }
  float z = sigmoidf_(pzv + az0+az1);
  float r = sigmoidf_(prv + ar0+ar1);
  float rh = r*ht;
  float ac0=0.f, ac1=0.f, ac2=0.f, ac3=0.f;
  #pragma unroll 8
  for (int k=0;k<64;k+=4){
    float r0 = __shfl(rh, k),   r1 = __shfl(rh, k+1);
    float r2 = __shfl(rh, k+2), r3 = __shfl(rh, k+3);
    ac0 += r0 * UhT[k*64+lane];     ac1 += r1 * UhT[(k+1)*64+lane];
    ac2 += r2 * UhT[(k+2)*64+lane]; ac3 += r3 * UhT[(k+3)*64+lane];
  }
  float cc = tanhf(pcv + (ac0+ac1)+(ac2+ac3));
  return z*ht + (1.f-z)*cc;
}

// coherent row read: plain fast path, then never-matching CAS for lagging lanes (bounded)
__device__ __forceinline__ unsigned int read_sync(unsigned int* p, int* budget){
  unsigned int u = *p;
  while (__any((int)(u == SENT)) && *budget > 0){
    if (u == SENT) u = atomicCAS(p, NEVER, NEVER);
    if (__any((int)(u == SENT))){ __builtin_amdgcn_s_sleep(2); --*budget; }
  }
  return u;
}

// ---- K2: FUSED gather + node transform + CLAIM-BASED dataflow (no polling) ----
// pending[i] = npc+1. Owner: pre-acts -> atomicExch pact -> atomicSub. Producers:
// publish row -> atomicSub each consumer. Whoever hits 0 computes the node (chain-
// walks via LDS stack). Any failure leaves row=SENT -> k_finish backstop computes it.
__device__ __forceinline__ void fused_body(int wid, int w, int lane, float xev,
    const float* __restrict__ WzT, const float* __restrict__ WrT,
    const float* __restrict__ WhT, const float* __restrict__ Wa,
    const float* __restrict__ bz, const float* __restrict__ br,
    const float* __restrict__ bh,
    const float* __restrict__ UzT, const float* __restrict__ UrT,
    const float* __restrict__ UhT, const int* __restrict__ tree,
    unsigned int* nhu, unsigned int* pact, int* pending,
    const int* __restrict__ rcnt, const int* __restrict__ rev,
    int* g_rem, unsigned int* gmax, int* stk)
{
  if (wid < NL){
    float az0=0.f, az1=0.f, ah0=0.f, ah1=0.f;
    #pragma unroll 8
    for (int k=0;k<64;k+=2){
      float x0 = __shfl(xev, k), x1 = __shfl(xev, k+1);
      az0 += x0 * WzT[k*64+lane];     az1 += x1 * WzT[(k+1)*64+lane];
      ah0 += x0 * WhT[k*64+lane];     ah1 += x1 * WhT[(k+1)*64+lane];
    }
    float z = sigmoidf_(az0+az1 + bz[lane]);
    float c = tanhf(ah0+ah1 + bh[lane]);
    atomicExch(&nhu[(size_t)wid*64 + lane], __float_as_uint((1.f-z)*c));
    return;                                        // leaves have no pending entry
  }
  int i = wid - NL;
  float az=0.f, ar=0.f, ah=0.f, aq=0.f;
  #pragma unroll 4
  for (int k=0;k<64;++k){
    float xk = __shfl(xev, k);
    az += xk * WzT[k*64+lane];
    ar += xk * WrT[k*64+lane];
    ah += xk * WhT[k*64+lane];
    aq += xk * Wa [k*64+lane];
  }
  float q0 = aq, pz0 = az + bz[lane], pr0 = ar + br[lane], pc0 = ah + bh[lane];
  unsigned int* pa = pact + (size_t)i*256;
  atomicExch(&pa[0*64+lane], __float_as_uint(q0));
  atomicExch(&pa[1*64+lane], __float_as_uint(pz0));
  atomicExch(&pa[2*64+lane], __float_as_uint(pc0));   // slot2 = pc, slot3 = pr (fixed order everywhere)
  atomicExch(&pa[3*64+lane], __float_as_uint(pr0));
  int nn = -1, sp = 0;
  if (lane == 0){
    if (atomicSub(&pending[i], 1) == 1) nn = i;    // owner token was last -> claim self
  }
  int next = __shfl(nn, 0);
  bool ownregs = true;
  while (next >= 0){
    int cur = next;
    int budget = 1<<16;
    float q, pzv, prv, pcv;
    if (ownregs && cur == i){ q=q0; pzv=pz0; prv=pr0; pcv=pc0; }
    else {
      unsigned int* pb = pact + (size_t)cur*256;
      q   = __uint_as_float(read_sync(&pb[0*64+lane], &budget));
      pzv = __uint_as_float(read_sync(&pb[1*64+lane], &budget));
      pcv = __uint_as_float(read_sync(&pb[2*64+lane], &budget));
      prv = __uint_as_float(read_sync(&pb[3*64+lane], &budget));
    }
    const int* tr = tree + cur*5;
    int c0=tr[0], c1=tr[1], c2=tr[2], c3=tr[3];
    unsigned int u0 = (c0>=0)? read_sync(&nhu[(size_t)c0*64+lane], &budget) : 0u;
    unsigned int u1 = (c1>=0)? read_sync(&nhu[(size_t)c1*64+lane], &budget) : 0u;
    unsigned int u2 = (c2>=0)? read_sync(&nhu[(size_t)c2*64+lane], &budget) : 0u;
    unsigned int u3 = (c3>=0)? read_sync(&nhu[(size_t)c3*64+lane], &budget) : 0u;
    bool bad = __any((int)(u0==SENT)) || __any((int)(u1==SENT)) ||
               __any((int)(u2==SENT)) || __any((int)(u3==SENT));
    nn = -1;
    if (!bad){
      float h = gru_compute(lane, c0,c1,c2,c3,
                            __uint_as_float(u0), __uint_as_float(u1),
                            __uint_as_float(u2), __uint_as_float(u3),
                            q, pzv, prv, pcv, UzT, UrT, UhT);
      atomicExch(&nhu[(size_t)(NL+cur)*64 + lane], __float_as_uint(h));  // publish @ L3
      atomicMax(&gmax[(cur&7)*64 + lane], umap(h));                      // fused max-pool
      if (lane == 0){
        atomicAdd(g_rem, -1);
        int rc = rcnt[cur]; if (rc > REVW) rc = REVW;
        for (int j = 0; j < rc; ++j){
          int cons = rev[cur*REVW + j];
          if (atomicSub(&pending[cons], 1) == 1){   // we completed its last dependency
            if (nn < 0) nn = cons;
            else if (sp < 12) stk[sp++] = cons;
            // stack full: drop -> row stays SENT -> finish backstop
          }
        }
      }
    } // bad: drop claim -> row stays SENT -> finish backstop
    if (lane == 0 && nn < 0 && sp > 0) nn = stk[--sp];
    next = __shfl(nn, 0);
    ownregs = false;
  }
}

__global__ void __launch_bounds__(256) k_fused(const float* __restrict__ xw,
    const int* __restrict__ xi, const float* __restrict__ ET,
    const float* __restrict__ WzT, const float* __restrict__ WrT,
    const float* __restrict__ WhT, const float* __restrict__ Wa,
    const float* __restrict__ bz, const float* __restrict__ br,
    const float* __restrict__ bh,
    const float* __restrict__ UzT, const float* __restrict__ UrT,
    const float* __restrict__ UhT, const int* __restrict__ tree,
    unsigned int* nhu, unsigned int* pact, int* pending,
    const int* __restrict__ rcnt, const int* __restrict__ rev,
    int* g_rem, unsigned int* gmax)
{
  __shared__ int stk_s[4][12];
  int w = threadIdx.x >> 6, lane = threadIdx.x & 63;
  int wid = blockIdx.x*4 + w;
  if (wid >= NN) return;
  int   idxl = (lane < KW) ? xi[wid*KW + lane] : 0;
  float wl   = (lane < KW) ? xw[wid*KW + lane] : 0.f;
  float xev = 0.f;
  #pragma unroll 8
  for (int k = 0; k < KW; ++k){
    int   vk = __shfl(idxl, k);
    float wk = __shfl(wl,   k);
    xev += wk * ET[vk*64 + lane];
  }
  fused_body(wid, w, lane, xev, WzT,WrT,WhT,Wa, bz,br,bh, UzT,UrT,UhT, tree,
             nhu, pact, pending, rcnt, rev, g_rem, gmax, stk_s[w]);
}

__global__ void __launch_bounds__(256) k_fused_direct(const float* __restrict__ xw,
    const int* __restrict__ xi, const float* __restrict__ E,
    const float* __restrict__ WzT, const float* __restrict__ WrT,
    const float* __restrict__ WhT, const float* __restrict__ Wa,
    const float* __restrict__ bz, const float* __restrict__ br,
    const float* __restrict__ bh,
    const float* __restrict__ UzT, const float* __restrict__ UrT,
    const float* __restrict__ UhT, const int* __restrict__ tree,
    unsigned int* nhu, unsigned int* pact, int* pending,
    const int* __restrict__ rcnt, const int* __restrict__ rev,
    int* g_rem, unsigned int* gmax)
{
  __shared__ int stk_s[4][12];
  int w = threadIdx.x >> 6, lane = threadIdx.x & 63;
  int wid = blockIdx.x*4 + w;
  if (wid >= NN) return;
  const float* wv = xw + wid*KW;
  const int*   v  = xi + wid*KW;
  const float* Erow = E + (size_t)lane*VC;
  float xev = 0.f;
  for (int k = 0; k < KW; ++k) xev += wv[k] * Erow[v[k]];
  fused_body(wid, w, lane, xev, WzT,WrT,WhT,Wa, bz,br,bh, UzT,UrT,UhT, tree,
             nhu, pact, pending, rcnt, rev, g_rem, gmax, stk_s[w]);
}

// ---- K3: finish = single-block cleanup backstop + final max reduce + head ----
__global__ void __launch_bounds__(256) k_finish(const int* __restrict__ tree,
    const unsigned int* __restrict__ pact,
    const float* __restrict__ UzT, const float* __restrict__ UrT,
    const float* __restrict__ UhT,
    unsigned int* nhu, int* g_rem, unsigned int* gmax,
    const float* __restrict__ Wout, const float* __restrict__ bout,
    float* __restrict__ out)
{
  __shared__ int cnt_s;
  __shared__ float sm[64];
  int w = threadIdx.x >> 6, lane = threadIdx.x & 63;
  int rem = *g_rem;
  while (rem > 0){
    if (threadIdx.x == 0) cnt_s = 0;
    __syncthreads();
    int my = 0;
    for (int i = w; i < NP; i += 4){
      if (nhu[(size_t)(NL+i)*64] != SENT) continue;      // done
      const int* tr = tree + i*5;
      int c0=tr[0], c1=tr[1], c2=tr[2], c3=tr[3];
      bool ready = (c0<0 || nhu[(size_t)c0*64] != SENT) &&
                   (c1<0 || nhu[(size_t)c1*64] != SENT) &&
                   (c2<0 || nhu[(size_t)c2*64] != SENT) &&
                   (c3<0 || nhu[(size_t)c3*64] != SENT);
      if (!ready) continue;
      float chv0 = (c0>=0)? __uint_as_float(nhu[(size_t)c0*64+lane]) : 0.f;
      float chv1 = (c1>=0)? __uint_as_float(nhu[(size_t)c1*64+lane]) : 0.f;
      float chv2 = (c2>=0)? __uint_as_float(nhu[(size_t)c2*64+lane]) : 0.f;
      float chv3 = (c3>=0)? __uint_as_float(nhu[(size_t)c3*64+lane]) : 0.f;
      const unsigned int* pb = pact + (size_t)i*256;
      float q   = __uint_as_float(pb[0*64+lane]);
      float pzv = __uint_as_float(pb[1*64+lane]);
      float pcv = __uint_as_float(pb[2*64+lane]);
      float prv = __uint_as_float(pb[3*64+lane]);
      float h = gru_compute(lane, c0,c1,c2,c3, chv0,chv1,chv2,chv3,
                            q, pzv, prv, pcv, UzT, UrT, UhT);
      nhu[(size_t)(NL+i)*64+lane] = __float_as_uint(h);  // same-block readers, plain ok
      atomicMax(&gmax[(i&7)*64+lane], umap(h));
      ++my;
    }
    if (lane==0 && my) atomicAdd(&cnt_s, my);
    __syncthreads();
    rem -= cnt_s;
    if (cnt_s == 0) break;          // safety: guarantees termination
    __syncthreads();
  }
  __syncthreads();
  if (w == 0){
    float m = -1e30f;
    #pragma unroll
    for (int c = 0; c < 8; ++c) m = fmaxf(m, uunmap(gmax[c*64+lane]));
    sm[lane] = m;                   // (not required, aids debugging)
    float s0 = Wout[0*64+lane]*m, s1 = Wout[1*64+lane]*m;
    float s2 = Wout[2*64+lane]*m, s3 = Wout[3*64+lane]*m;
    #pragma unroll
    for (int off=32; off; off>>=1){
      s0 += __shfl_xor(s0, off); s1 += __shfl_xor(s1, off);
      s2 += __shfl_xor(s2, off); s3 += __shfl_xor(s3, off);
    }
    s0 += bout[0]; s1 += bout[1]; s2 += bout[2]; s3 += bout[3];
    float mx = fmaxf(fmaxf(s0,s1), fmaxf(s2,s3));
    float e0=expf(s0-mx), e1=expf(s1-mx), e2=expf(s2-mx), e3=expf(s3-mx);
    float inv = 1.f/(e0+e1+e2+e3);
    if (lane==0){
      out[0]=e0*inv; out[1]=e1*inv; out[2]=e2*inv; out[3]=e3*inv;
    }
  }
}

__global__ void k_ws_sentinel(float* out, float wsmb){
  if (threadIdx.x < 4) out[threadIdx.x] = wsmb;
}

extern "C" void kernel_launch(void* const* d_in, const int* in_sizes, int n_in,
                              void* d_out, int out_size, void* d_ws, size_t ws_size,
                              hipStream_t stream){
  const float* x_word = (const float*)d_in[0];
  const int*   x_index= (const int*)d_in[1];
  const int*   tree   = (const int*)d_in[2];
  const float* E      = (const float*)d_in[3];
  const float* Wz     = (const float*)d_in[4];
  const float* Uz     = (const float*)d_in[5];
  const float* bz     = (const float*)d_in[6];
  const float* Wr     = (const float*)d_in[7];
  const float* Ur     = (const float*)d_in[8];
  const float* br     = (const float*)d_in[9];
  const float* Wh     = (const float*)d_in[10];
  const float* Uh     = (const float*)d_in[11];
  const float* bh     = (const float*)d_in[12];
  const float* Wa     = (const float*)d_in[13];
  const float* Wout   = (const float*)d_in[14];
  const float* bout   = (const float*)d_in[15];
  float* out = (float*)d_out;

  float* ws = (float*)d_ws;

  // Layout: ET (6,400,000 f, full path) | pact (2,097,152) | nodeh (1,048,576) |
  //         WT (24,576) | pending NP | rcnt NP | rev NP*8 | g_rem 1 | gmax 512.
  const size_t R0_FULL = 6400000;
  const size_t TAIL = (size_t)2097152 + 1048576 + 24576 + NP + NP + NP*REVW + 1 + 512;
  const size_t FULL_NEED = (R0_FULL + TAIL) * 4;   // ~38.6 MB (r8 proved ~38.7 available)
  const size_t FB_NEED   = TAIL * 4;               // ~13.0 MB

  bool full = (ws_size >= FULL_NEED);
  bool fb   = (!full && ws_size >= FB_NEED);
  if (!full && !fb){
    k_ws_sentinel<<<1, 64, 0, stream>>>(out, (float)(ws_size >> 20));
    return;
  }

  float* ET = ws;
  size_t r0 = full ? R0_FULL : 0;
  unsigned int* pact  = (unsigned int*)(ws + r0);    // NP*256
  unsigned int* nhu   = pact + (size_t)NP*256;       // NN*64
  float* WT   = (float*)(nhu + (size_t)NN*64);       // 24,576
  int* pending = (int*)(WT + 24576);                 // NP
  int* rcnt    = pending + NP;                       // NP
  int* rev     = rcnt + NP;                          // NP*REVW
  int* g_rem   = rev + NP*REVW;                      // 1
  unsigned int* gmax = (unsigned int*)(g_rem + 1);   // 512
  float* WzT = WT,       *WrT = WT+4096,  *WhT = WT+8192;
  float* UzT = WT+12288, *UrT = WT+16384, *UhT = WT+20480;

  hipMemsetAsync(rcnt, 0, NP*sizeof(int), stream);   // before setup's atomicAdds

  int et_blocks = full ? (VC+63)/64 : 0;             // 1563 or 0
  int nblocks = et_blocks + 6 + 4096 + 8192 + NP/256;
  k_setup<<<nblocks, 256, 0, stream>>>(E, ET, Wz, Wr, Wh, Uz, Ur, Uh, WT,
                                       nhu, pact, tree, pending, rcnt, rev,
                                       g_rem, gmax, et_blocks);
  if (full)
    k_fused<<<NN/4, 256, 0, stream>>>(x_word, x_index, ET, WzT, WrT, WhT, Wa,
                                      bz, br, bh, UzT, UrT, UhT, tree,
                                      nhu, pact, pending, rcnt, rev, g_rem, gmax);
  else
    k_fused_direct<<<NN/4, 256, 0, stream>>>(x_word, x_index, E, WzT, WrT, WhT, Wa,
                                             bz, br, bh, UzT, UrT, UhT, tree,
                                             nhu, pact, pending, rcnt, rev, g_rem, gmax);
  k_finish<<<1, 256, 0, stream>>>(tree, pact, UzT, UrT, UhT, nhu, g_rem, gmax,
                                  Wout, bout, out);
}

// Round 15
// 163.792 us; speedup vs baseline: 1.6457x; 1.6457x over previous
//
#include <hip/hip_runtime.h>
#include <math.h>

#define NN 16384
#define NP 8192
#define NL 8192
#define KW 32
#define VC 100000
#define SENT  0xFFFFFFFFu
#define NEVER 0xFFFFFFFEu     // CAS compare that never matches real data -> pure coherent read
#define UMAP_NEGINF 0x007FFFFFu

__device__ __forceinline__ float sigmoidf_(float x){ return 1.0f/(1.0f+expf(-x)); }
__device__ __forceinline__ unsigned int umap(float f){
  unsigned int b = __float_as_uint(f);
  return (b & 0x80000000u) ? ~b : (b | 0x80000000u);
}
__device__ __forceinline__ float uunmap(unsigned int u){
  unsigned int b = (u & 0x80000000u) ? (u & 0x7FFFFFFFu) : ~u;
  return __uint_as_float(b);
}

// ---- K1: setup: ET transpose | WT transposes | node_h->SENT | g_rem/gmax init ----
__global__ void __launch_bounds__(256) k_setup(const float* __restrict__ E, float* __restrict__ ET,
    const float* __restrict__ Wz, const float* __restrict__ Wr, const float* __restrict__ Wh,
    const float* __restrict__ Uz, const float* __restrict__ Ur, const float* __restrict__ Uh,
    float* __restrict__ WT, unsigned int* node_h, int* g_rem, unsigned int* gmax,
    int et_blocks){
  __shared__ float tile[64][65];
  int b = blockIdx.x;
  int lane = threadIdx.x & 63, ty = threadIdx.x >> 6;
  if (b < et_blocks){
    int v0 = b*64;
    for (int h = ty; h < 64; h += 4){
      int v = v0 + lane;
      tile[h][lane] = (v < VC) ? E[(size_t)h*VC + v] : 0.f;
    }
    __syncthreads();
    for (int vv = ty; vv < 64; vv += 4){
      int v = v0 + vv;
      if (v < VC) ET[v*64 + lane] = tile[lane][vv];
    }
  } else if (b < et_blocks + 6){
    int m = b - et_blocks;
    const float* src = (m==0)?Wz:(m==1)?Wr:(m==2)?Wh:(m==3)?Uz:(m==4)?Ur:Uh;
    float* dst = WT + m*4096;
    for (int h = ty; h < 64; h += 4) tile[h][lane] = src[h*64 + lane];
    __syncthreads();
    for (int k = ty; k < 64; k += 4) dst[k*64 + lane] = tile[lane][k];
  } else if (b < et_blocks + 6 + 4096){
    size_t idx = (size_t)(b - et_blocks - 6)*256 + threadIdx.x;   // NN*64 dwords
    node_h[idx] = SENT;
  } else {
    int idx = (b - et_blocks - 6 - 4096)*256 + threadIdx.x;       // 2 blocks
    if (idx < 512) gmax[idx] = UMAP_NEGINF;
    if (idx == 0) *g_rem = NP;
  }
}

// ---- word0-last publish: row[0] != SENT  =>  whole row committed at L3 ----
__device__ __forceinline__ void publish_row(unsigned int* row, int lane, float h){
  unsigned int hb = __float_as_uint(h);
  if (lane) atomicExch(&row[lane], hb);
  asm volatile("s_waitcnt vmcnt(0)" ::: "memory");   // drain lanes 1..63 exchanges
  if (!lane) atomicExch(&row[0], hb);
}

// ---- shared GRU math ----
__device__ __forceinline__ float gru_compute(int lane,
    int c0,int c1,int c2,int c3,
    float chv0,float chv1,float chv2,float chv3,
    float q, float pzv, float prv, float pcv,
    const float* __restrict__ UzT, const float* __restrict__ UrT,
    const float* __restrict__ UhT)
{
  float d0=q*chv0, d1=q*chv1, d2=q*chv2, d3=q*chv3;
  #pragma unroll
  for (int off=32; off; off>>=1){
    d0 += __shfl_xor(d0, off); d1 += __shfl_xor(d1, off);
    d2 += __shfl_xor(d2, off); d3 += __shfl_xor(d3, off);
  }
  float l0 = (c0>=0)? sigmoidf_(d0) : -1e30f;
  float l1 = (c1>=0)? sigmoidf_(d1) : -1e30f;
  float l2 = (c2>=0)? sigmoidf_(d2) : -1e30f;
  float l3 = (c3>=0)? sigmoidf_(d3) : -1e30f;
  float mx = fmaxf(fmaxf(l0,l1), fmaxf(l2,l3));
  float e0=expf(l0-mx), e1=expf(l1-mx), e2=expf(l2-mx), e3=expf(l3-mx);
  float inv = 1.f/(e0+e1+e2+e3);
  float ht = (e0*chv0 + e1*chv1 + e2*chv2 + e3*chv3)*inv;
  float az0=0.f, az1=0.f, ar0=0.f, ar1=0.f;
  #pragma unroll 8
  for (int k=0;k<64;k+=2){
    float h0 = __shfl(ht, k), h1 = __shfl(ht, k+1);
    az0 += h0 * UzT[k*64+lane];     az1 += h1 * UzT[(k+1)*64+lane];
    ar0 += h0 * UrT[k*64+lane];     ar1 += h1 * UrT[(k+1)*64+lane];
  }
  float z = sigmoidf_(pzv + az0+az1);
  float r = sigmoidf_(prv + ar0+ar1);
  float rh = r*ht;
  float ac0=0.f, ac1=0.f, ac2=0.f, ac3=0.f;
  #pragma unroll 8
  for (int k=0;k<64;k+=4){
    float r0 = __shfl(rh, k),   r1 = __shfl(rh, k+1);
    float r2 = __shfl(rh, k+2), r3 = __shfl(rh, k+3);
    ac0 += r0 * UhT[k*64+lane];     ac1 += r1 * UhT[(k+1)*64+lane];
    ac2 += r2 * UhT[(k+2)*64+lane]; ac3 += r3 * UhT[(k+3)*64+lane];
  }
  float cc = tanhf(pcv + (ac0+ac1)+(ac2+ac3));
  return z*ht + (1.f-z)*cc;
}

// ---- K2: FUSED gather + node transform + single-dispatch dataflow scan ----
// r12 structure + contention cuts:
//  publish: word0-last (vmcnt-fenced) -> word0 != SENT implies full row valid
//  detect : lanes 0-3 poll only their child's WORD 0, two-phase constant backoff
//  gather : plain wave-load, repair stale-SENT lanes with one CAS (guaranteed
//           non-SENT by the publish protocol)
// Failsafe: bounded rounds; on timeout leave row SENT -> k_finish backstop.
__device__ __forceinline__ void fused_body(int wid, int lane, float xev,
    const float* __restrict__ WzT, const float* __restrict__ WrT,
    const float* __restrict__ WhT, const float* __restrict__ Wa,
    const float* __restrict__ bz, const float* __restrict__ br,
    const float* __restrict__ bh,
    const float* __restrict__ UzT, const float* __restrict__ UrT,
    const float* __restrict__ UhT, const int* __restrict__ tree,
    unsigned int* nhu, float* pz, float* pr, float* pc, float* qa,
    int* g_rem, unsigned int* gmax)
{
  if (wid < NL){
    float az0=0.f, az1=0.f, ah0=0.f, ah1=0.f;
    #pragma unroll 8
    for (int k=0;k<64;k+=2){
      float x0 = __shfl(xev, k), x1 = __shfl(xev, k+1);
      az0 += x0 * WzT[k*64+lane];     az1 += x1 * WzT[(k+1)*64+lane];
      ah0 += x0 * WhT[k*64+lane];     ah1 += x1 * WhT[(k+1)*64+lane];
    }
    float z = sigmoidf_(az0+az1 + bz[lane]);
    float c = tanhf(ah0+ah1 + bh[lane]);
    publish_row(&nhu[(size_t)wid*64], lane, (1.f-z)*c);
    return;
  }
  int i = wid - NL;
  float az=0.f, ar=0.f, ah=0.f, aq=0.f;
  #pragma unroll 4
  for (int k=0;k<64;++k){
    float xk = __shfl(xev, k);
    az += xk * WzT[k*64+lane];
    ar += xk * WrT[k*64+lane];
    ah += xk * WhT[k*64+lane];
    aq += xk * Wa [k*64+lane];
  }
  float q = aq, pzv = az + bz[lane], prv = ar + br[lane], pcv = ah + bh[lane];
  // store for the finish backstop (fast path consumes the registers)
  pz[i*64+lane] = pzv; pr[i*64+lane] = prv; pc[i*64+lane] = pcv; qa[i*64+lane] = q;
  const int* tr = tree + i*5;
  int c0=tr[0], c1=tr[1], c2=tr[2], c3=tr[3];
  // fast path: plain wave-loads (stale can only read SENT -> routed to poll)
  unsigned int u0 = (c0>=0)? nhu[(size_t)c0*64+lane] : 0u;
  unsigned int u1 = (c1>=0)? nhu[(size_t)c1*64+lane] : 0u;
  unsigned int u2 = (c2>=0)? nhu[(size_t)c2*64+lane] : 0u;
  unsigned int u3 = (c3>=0)? nhu[(size_t)c3*64+lane] : 0u;
  bool anyS = __any((int)(u0==SENT)) || __any((int)(u1==SENT)) ||
              __any((int)(u2==SENT)) || __any((int)(u3==SENT));
  if (anyS){
    // word0 poll: lanes 0-3 each own one child; 1-4 CAS per wave per round
    int myc = (lane==0)?c0:(lane==1)?c1:(lane==2)?c2:(lane==3)?c3:-1;
    bool need = (lane < 4) && (myc >= 0);
    unsigned int* myp = &nhu[(size_t)(need ? myc : 0)*64];
    bool rdy = !need;
    if (need) rdy = (atomicCAS(myp, NEVER, NEVER) != SENT);
    int rounds = 0;
    while (!__all((int)rdy)){
      if (rounds < 4) __builtin_amdgcn_s_sleep(1);   // ~64 cyc (fast detect early)
      else            __builtin_amdgcn_s_sleep(8);   // ~512 cyc (parked)
      if (!rdy) rdy = (atomicCAS(myp, NEVER, NEVER) != SENT);
      if (++rounds > (1<<14)) break;                 // failsafe -> finish backstop
    }
    if (!__all((int)rdy)) return;
    // repair: only stale-SENT lanes CAS-read; protocol guarantees non-SENT now
    if (c0>=0 && u0==SENT) u0 = atomicCAS(&nhu[(size_t)c0*64+lane], NEVER, NEVER);
    if (c1>=0 && u1==SENT) u1 = atomicCAS(&nhu[(size_t)c1*64+lane], NEVER, NEVER);
    if (c2>=0 && u2==SENT) u2 = atomicCAS(&nhu[(size_t)c2*64+lane], NEVER, NEVER);
    if (c3>=0 && u3==SENT) u3 = atomicCAS(&nhu[(size_t)c3*64+lane], NEVER, NEVER);
    if (__any((int)(u0==SENT)) || __any((int)(u1==SENT)) ||
        __any((int)(u2==SENT)) || __any((int)(u3==SENT))) return;  // belt+braces
  }
  float h = gru_compute(lane, c0,c1,c2,c3,
                        __uint_as_float(u0), __uint_as_float(u1),
                        __uint_as_float(u2), __uint_as_float(u3),
                        q, pzv, prv, pcv, UzT, UrT, UhT);
  publish_row(&nhu[(size_t)(NL+i)*64], lane, h);
  atomicMax(&gmax[(i&7)*64 + lane], umap(h));      // fused max-pool
  if (lane==0) atomicAdd(g_rem, -1);
}

__global__ void __launch_bounds__(256) k_fused(const float* __restrict__ xw,
    const int* __restrict__ xi, const float* __restrict__ ET,
    const float* __restrict__ WzT, const float* __restrict__ WrT,
    const float* __restrict__ WhT, const float* __restrict__ Wa,
    const float* __restrict__ bz, const float* __restrict__ br,
    const float* __restrict__ bh,
    const float* __restrict__ UzT, const float* __restrict__ UrT,
    const float* __restrict__ UhT, const int* __restrict__ tree,
    unsigned int* nhu, float* pz, float* pr, float* pc, float* qa,
    int* g_rem, unsigned int* gmax)
{
  int wid = blockIdx.x*4 + (threadIdx.x>>6);
  int lane = threadIdx.x & 63;
  if (wid >= NN) return;
  int   idxl = (lane < KW) ? xi[wid*KW + lane] : 0;
  float wl   = (lane < KW) ? xw[wid*KW + lane] : 0.f;
  float xev = 0.f;
  #pragma unroll 8
  for (int k = 0; k < KW; ++k){
    int   vk = __shfl(idxl, k);
    float wk = __shfl(wl,   k);
    xev += wk * ET[vk*64 + lane];
  }
  fused_body(wid, lane, xev, WzT,WrT,WhT,Wa, bz,br,bh, UzT,UrT,UhT, tree,
             nhu, pz,pr,pc,qa, g_rem, gmax);
}

__global__ void __launch_bounds__(256) k_fused_direct(const float* __restrict__ xw,
    const int* __restrict__ xi, const float* __restrict__ E,
    const float* __restrict__ WzT, const float* __restrict__ WrT,
    const float* __restrict__ WhT, const float* __restrict__ Wa,
    const float* __restrict__ bz, const float* __restrict__ br,
    const float* __restrict__ bh,
    const float* __restrict__ UzT, const float* __restrict__ UrT,
    const float* __restrict__ UhT, const int* __restrict__ tree,
    unsigned int* nhu, float* pz, float* pr, float* pc, float* qa,
    int* g_rem, unsigned int* gmax)
{
  int wid = blockIdx.x*4 + (threadIdx.x>>6);
  int lane = threadIdx.x & 63;
  if (wid >= NN) return;
  const float* wv = xw + wid*KW;
  const int*   v  = xi + wid*KW;
  const float* Erow = E + (size_t)lane*VC;
  float xev = 0.f;
  for (int k = 0; k < KW; ++k) xev += wv[k] * Erow[v[k]];
  fused_body(wid, lane, xev, WzT,WrT,WhT,Wa, bz,br,bh, UzT,UrT,UhT, tree,
             nhu, pz,pr,pc,qa, g_rem, gmax);
}

// ---- K3: finish = single-block cleanup backstop + final max reduce + head ----
__global__ void __launch_bounds__(256) k_finish(const int* __restrict__ tree,
    const float* __restrict__ qa, const float* __restrict__ pz,
    const float* __restrict__ pr, const float* __restrict__ pc,
    const float* __restrict__ UzT, const float* __restrict__ UrT,
    const float* __restrict__ UhT,
    unsigned int* nhu, int* g_rem, unsigned int* gmax,
    const float* __restrict__ Wout, const float* __restrict__ bout,
    float* __restrict__ out)
{
  __shared__ int cnt_s;
  int w = threadIdx.x >> 6, lane = threadIdx.x & 63;
  int rem = *g_rem;
  while (rem > 0){
    if (threadIdx.x == 0) cnt_s = 0;
    __syncthreads();
    int my = 0;
    for (int i = w; i < NP; i += 4){
      if (nhu[(size_t)(NL+i)*64] != SENT) continue;     // already done
      const int* tr = tree + i*5;
      int c0=tr[0], c1=tr[1], c2=tr[2], c3=tr[3];
      bool ready = (c0<0 || nhu[(size_t)c0*64] != SENT) &&
                   (c1<0 || nhu[(size_t)c1*64] != SENT) &&
                   (c2<0 || nhu[(size_t)c2*64] != SENT) &&
                   (c3<0 || nhu[(size_t)c3*64] != SENT);
      if (!ready) continue;
      float chv0 = (c0>=0)? __uint_as_float(nhu[(size_t)c0*64+lane]) : 0.f;
      float chv1 = (c1>=0)? __uint_as_float(nhu[(size_t)c1*64+lane]) : 0.f;
      float chv2 = (c2>=0)? __uint_as_float(nhu[(size_t)c2*64+lane]) : 0.f;
      float chv3 = (c3>=0)? __uint_as_float(nhu[(size_t)c3*64+lane]) : 0.f;
      float h = gru_compute(lane, c0,c1,c2,c3, chv0,chv1,chv2,chv3,
                            qa[i*64+lane], pz[i*64+lane], pr[i*64+lane], pc[i*64+lane],
                            UzT, UrT, UhT);
      nhu[(size_t)(NL+i)*64+lane] = __float_as_uint(h); // same-block readers
      atomicMax(&gmax[(i&7)*64+lane], umap(h));
      ++my;
    }
    if (lane==0 && my) atomicAdd(&cnt_s, my);
    __syncthreads();
    rem -= cnt_s;
    if (cnt_s == 0) break;            // guarantees termination
    __syncthreads();
  }
  __syncthreads();
  if (w == 0){
    float m = -1e30f;
    #pragma unroll
    for (int c = 0; c < 8; ++c){
      unsigned int g = atomicCAS(&gmax[c*64+lane], NEVER, NEVER);  // coherent read
      m = fmaxf(m, uunmap(g));
    }
    float s0 = Wout[0*64+lane]*m, s1 = Wout[1*64+lane]*m;
    float s2 = Wout[2*64+lane]*m, s3 = Wout[3*64+lane]*m;
    #pragma unroll
    for (int off=32; off; off>>=1){
      s0 += __shfl_xor(s0, off); s1 += __shfl_xor(s1, off);
      s2 += __shfl_xor(s2, off); s3 += __shfl_xor(s3, off);
    }
    s0 += bout[0]; s1 += bout[1]; s2 += bout[2]; s3 += bout[3];
    float mx = fmaxf(fmaxf(s0,s1), fmaxf(s2,s3));
    float e0=expf(s0-mx), e1=expf(s1-mx), e2=expf(s2-mx), e3=expf(s3-mx);
    float inv = 1.f/(e0+e1+e2+e3);
    if (lane==0){
      out[0]=e0*inv; out[1]=e1*inv; out[2]=e2*inv; out[3]=e3*inv;
    }
  }
}

__global__ void k_ws_sentinel(float* out, float wsmb){
  if (threadIdx.x < 4) out[threadIdx.x] = wsmb;
}

extern "C" void kernel_launch(void* const* d_in, const int* in_sizes, int n_in,
                              void* d_out, int out_size, void* d_ws, size_t ws_size,
                              hipStream_t stream){
  const float* x_word = (const float*)d_in[0];
  const int*   x_index= (const int*)d_in[1];
  const int*   tree   = (const int*)d_in[2];
  const float* E      = (const float*)d_in[3];
  const float* Wz     = (const float*)d_in[4];
  const float* Uz     = (const float*)d_in[5];
  const float* bz     = (const float*)d_in[6];
  const float* Wr     = (const float*)d_in[7];
  const float* Ur     = (const float*)d_in[8];
  const float* br     = (const float*)d_in[9];
  const float* Wh     = (const float*)d_in[10];
  const float* Uh     = (const float*)d_in[11];
  const float* bh     = (const float*)d_in[12];
  const float* Wa     = (const float*)d_in[13];
  const float* Wout   = (const float*)d_in[14];
  const float* bout   = (const float*)d_in[15];
  float* out = (float*)d_out;

  float* ws = (float*)d_ws;

  // Layout: ET (6,400,000 f, full path only; read by k_fused) | qa/pz/pr/pc (2,097,152)
  //       | nodeh (1,048,576) | WT (24,576) | g_rem (1) | gmax (512).
  const size_t R0_FULL = 6400000;
  const size_t TAIL = (size_t)2097152 + 1048576 + 24576 + 1 + 512;
  const size_t FULL_NEED = (R0_FULL + TAIL) * 4;   // ~38.3 MB (r12/r13 proved available)
  const size_t FB_NEED   = TAIL * 4;               // ~12.7 MB

  bool full = (ws_size >= FULL_NEED);
  bool fb   = (!full && ws_size >= FB_NEED);
  if (!full && !fb){
    k_ws_sentinel<<<1, 64, 0, stream>>>(out, (float)(ws_size >> 20));
    return;
  }

  float* ET = ws;                                  // full path only
  size_t r0 = full ? R0_FULL : 0;
  float* qa    = ws + r0;                          // 4 x 524,288
  float* pz    = qa + 524288;
  float* pr    = pz + 524288;
  float* pc    = pr + 524288;
  unsigned int* nhu = (unsigned int*)(pc + 524288);  // NN*64
  float* WT    = (float*)(nhu + (size_t)NN*64);    // 24,576
  int*   g_rem = (int*)(WT + 24576);               // 1
  unsigned int* gmax = (unsigned int*)(g_rem + 1); // 512
  float* WzT = WT,       *WrT = WT+4096,  *WhT = WT+8192;
  float* UzT = WT+12288, *UrT = WT+16384, *UhT = WT+20480;

  int et_blocks = full ? (VC+63)/64 : 0;           // 1563 or 0
  k_setup<<<et_blocks + 6 + 4096 + 2, 256, 0, stream>>>(
      E, ET, Wz, Wr, Wh, Uz, Ur, Uh, WT, nhu, g_rem, gmax, et_blocks);
  if (full)
    k_fused<<<NN/4, 256, 0, stream>>>(x_word, x_index, ET, WzT, WrT, WhT, Wa,
                                      bz, br, bh, UzT, UrT, UhT, tree,
                                      nhu, pz, pr, pc, qa, g_rem, gmax);
  else
    k_fused_direct<<<NN/4, 256, 0, stream>>>(x_word, x_index, E, WzT, WrT, WhT, Wa,
                                             bz, br, bh, UzT, UrT, UhT, tree,
                                             nhu, pz, pr, pc, qa, g_rem, gmax);
  k_finish<<<1, 256, 0, stream>>>(tree, qa, pz, pr, pc, UzT, UrT, UhT,
                                  nhu, g_rem, gmax, Wout, bout, out);
}